// Round 15
// baseline (183.861 us; speedup 1.0000x reference)
//
#include <hip/hip_runtime.h>
#include <math.h>

#define B_  16
#define L_  2048
#define D_  512
#define K_  7
#define Q_  (B_*L_*D_)   // 16777216 elements per output tensor

// bf16 helpers (RNE pack, shift unpack)
__device__ __forceinline__ ushort f2bf(float x){
  uint u = __float_as_uint(x);
  u += 0x7FFFu + ((u >> 16) & 1u);
  return (ushort)(u >> 16);
}
__device__ __forceinline__ float bf2f(ushort h){
  return __uint_as_float((uint)h << 16);
}

// ---------------------------------------------------------------------------
// Kernel A (best form, R8/R11): tiled transpose (B,L,D) f32 -> (B,D,L) bf16.
// One tensor per block -> 16.9 KiB LDS, high concurrency. (Multi-tile
// pipelining regressed twice: R10, R12 — keep one tile / many blocks.)
// ---------------------------------------------------------------------------
__global__ __launch_bounds__(256) void kA(const float* __restrict__ q,
                                          const float* __restrict__ k,
                                          ushort* __restrict__ qT,
                                          ushort* __restrict__ kT) {
  __shared__ float t[64][65];
  const int l0 = blockIdx.x * 64, d0 = blockIdx.y * 64;
  const int b = blockIdx.z & 15, ten = blockIdx.z >> 4;
  const float*  __restrict__ src = ten ? k : q;
  ushort* __restrict__ dst = ten ? kT : qT;
  const int tid = threadIdx.x;
  const size_t ibase = (size_t)b * L_ * D_;
#pragma unroll
  for (int u = 0; u < 4; ++u) {
    const int idx = tid + (u << 8);          // 0..1023
    const int row = idx >> 4;                // l within tile
    const int c   = (idx & 15) << 2;         // d within tile (float4)
    const float4 v = *(const float4*)&src[ibase + (size_t)(l0 + row) * D_ + d0 + c];
    t[row][c + 0] = v.x; t[row][c + 1] = v.y;
    t[row][c + 2] = v.z; t[row][c + 3] = v.w;
  }
  __syncthreads();
  const size_t obase = (size_t)b * D_ * L_;
#pragma unroll
  for (int u = 0; u < 4; ++u) {
    const int idx  = tid + (u << 8);
    const int drow = idx >> 4;               // d within tile
    const int c    = (idx & 15) << 2;        // l within tile (ushort4)
    ushort4 o;
    o.x = f2bf(t[c + 0][drow]); o.y = f2bf(t[c + 1][drow]);
    o.z = f2bf(t[c + 2][drow]); o.w = f2bf(t[c + 3][drow]);
    *(ushort4*)&dst[obase + (size_t)(d0 + drow) * L_ + l0 + c] = o;
  }
}

// ---------------------------------------------------------------------------
// Kernel B: 4 channels/block, 256 threads, 64 KiB LDS (two ping-pong pairs).
// R15: dual-stream passes FUSED so the twiddle chain (sincos + powers) is
// computed once per thread per pass and shared by both streams.
// ---------------------------------------------------------------------------
struct cf { float r, i; };
__device__ __forceinline__ cf cadd(cf a, cf b){ return {a.r+b.r, a.i+b.i}; }
__device__ __forceinline__ cf csub(cf a, cf b){ return {a.r-b.r, a.i-b.i}; }
__device__ __forceinline__ cf cmul(cf a, cf b){ return {a.r*b.r - a.i*b.i, a.r*b.i + a.i*b.r}; }
template<bool INV> __device__ __forceinline__ cf rot90(cf x){
  return INV ? cf{-x.i, x.r} : cf{x.i, -x.r};   // * +/- i
}
__device__ __forceinline__ int swz(int a){ return a ^ (((a >> 4) ^ (a >> 8)) & 15); }
__device__ __forceinline__ cf ldx(const float2* __restrict__ p, int i){
  const float2 v = p[swz(i)]; return {v.x, v.y};
}
__device__ __forceinline__ void stx(float2* __restrict__ p, int i, cf v){
  p[swz(i)] = {v.r, v.i};
}

template<bool INV>
__device__ __forceinline__ void dft8(cf a[8], cf b[8]) {
  const float H = 0.70710678118654752440f;
  cf t0 = cadd(a[0],a[4]), t1 = cadd(a[1],a[5]), t2 = cadd(a[2],a[6]), t3 = cadd(a[3],a[7]);
  cf u0 = csub(a[0],a[4]), u1 = csub(a[1],a[5]), u2 = csub(a[2],a[6]), u3 = csub(a[3],a[7]);
  const cf w1 = INV ? cf{H,  H} : cf{ H, -H};
  const cf w3 = INV ? cf{-H, H} : cf{-H, -H};
  u1 = cmul(u1, w1);
  u2 = rot90<INV>(u2);
  u3 = cmul(u3, w3);
  { cf s0 = cadd(t0,t2), s1 = csub(t0,t2), s2 = cadd(t1,t3), s3 = rot90<INV>(csub(t1,t3));
    b[0]=cadd(s0,s2); b[4]=csub(s0,s2); b[2]=cadd(s1,s3); b[6]=csub(s1,s3); }
  { cf s0 = cadd(u0,u2), s1 = csub(u0,u2), s2 = cadd(u1,u3), s3 = rot90<INV>(csub(u1,u3));
    b[1]=cadd(s0,s2); b[5]=csub(s0,s2); b[3]=cadd(s1,s3); b[7]=csub(s1,s3); }
}

#define ANG_ (-0.0030679615757712823f)   // -2*pi/2048

struct tw7 { cf w1, w2, w3, w4, w5, w6, w7; };
__device__ __forceinline__ tw7 make_tw(int ps, float sgn_ang) {
  float sn, cs;
  __sincosf(sgn_ang * (float)ps, &sn, &cs);
  tw7 t;
  t.w1 = {cs, sn};
  t.w2 = cmul(t.w1, t.w1);
  t.w3 = cmul(t.w2, t.w1);
  t.w4 = cmul(t.w2, t.w2);
  t.w5 = cmul(t.w3, t.w2);
  t.w6 = cmul(t.w3, t.w3);
  t.w7 = cmul(t.w4, t.w3);
  return t;
}
__device__ __forceinline__ void apply_tw(cf b[8], const tw7& t) {
  b[1]=cmul(b[1],t.w1); b[2]=cmul(b[2],t.w2); b[3]=cmul(b[3],t.w3);
  b[4]=cmul(b[4],t.w4); b[5]=cmul(b[5],t.w5); b[6]=cmul(b[6],t.w6);
  b[7]=cmul(b[7],t.w7);
}

// Dual forward pass 1 fused with bf16 global loads; shared twiddles (p=j).
__device__ __forceinline__ void pass8_first_dual(const ushort* __restrict__ qA,
                                                 const ushort* __restrict__ kA_,
                                                 float2* __restrict__ dA,
                                                 const ushort* __restrict__ qB,
                                                 const ushort* __restrict__ kB_,
                                                 float2* __restrict__ dB, int j) {
  cf a[8], bA[8], a2[8], bB[8];
#pragma unroll
  for (int l = 0; l < 8; ++l) {
    const int ix = j + (l << 8);
    a[l]  = {bf2f(qA[ix]),  bf2f(kA_[ix])};
    a2[l] = {bf2f(qB[ix]),  bf2f(kB_[ix])};
  }
  dft8<false>(a, bA);
  dft8<false>(a2, bB);
  const tw7 t = make_tw(j, ANG_);
  apply_tw(bA, t);
  apply_tw(bB, t);
#pragma unroll
  for (int k = 0; k < 8; ++k) {
    stx(dA, 8 * j + k, bA[k]);   // wb = j + 7*j = 8j (s=1)
    stx(dB, 8 * j + k, bB[k]);
  }
}

// Dual mid pass; shared twiddles.
template<int LOG2S, bool INV>
__device__ __forceinline__ void pass8_dual(const float2* __restrict__ sA,
                                           float2* __restrict__ dA,
                                           const float2* __restrict__ sB,
                                           float2* __restrict__ dB, int j) {
  const int p = j >> LOG2S;
  cf a[8], bA[8], a2[8], bB[8];
#pragma unroll
  for (int l = 0; l < 8; ++l) a[l]  = ldx(sA, j + (l << 8));
#pragma unroll
  for (int l = 0; l < 8; ++l) a2[l] = ldx(sB, j + (l << 8));
  dft8<INV>(a, bA);
  dft8<INV>(a2, bB);
  const tw7 t = make_tw(p << LOG2S, INV ? -ANG_ : ANG_);
  apply_tw(bA, t);
  apply_tw(bB, t);
  const int wb = j + 7 * (p << LOG2S);
#pragma unroll
  for (int k = 0; k < 8; ++k) {
    stx(dA, wb + (k << LOG2S), bA[k]);
    stx(dB, wb + (k << LOG2S), bB[k]);
  }
}

// Forward final radix-4 (s=512, twiddle-free), LDS->LDS, outputs ALSO kept
// in regs: pa[m] holds f = j + 256m.
__device__ __forceinline__ void pass4_fwd_reg(const float2* __restrict__ src,
                                              float2* __restrict__ dst, int j,
                                              cf pa[8]) {
#pragma unroll
  for (int h = 0; h < 2; ++h) {
    const int jj = j + (h << 8);
    cf a0 = ldx(src, jj), a1 = ldx(src, jj + 512), a2 = ldx(src, jj + 1024), a3 = ldx(src, jj + 1536);
    cf s0 = cadd(a0,a2), s1 = csub(a0,a2), s2 = cadd(a1,a3), s3 = rot90<false>(csub(a1,a3));
    const cf o0 = cadd(s0,s2), o1 = cadd(s1,s3), o2 = csub(s0,s2), o3 = csub(s1,s3);
    stx(dst, jj,        o0);
    stx(dst, jj + 512,  o1);
    stx(dst, jj + 1024, o2);
    stx(dst, jj + 1536, o3);
    pa[h]     = o0;
    pa[h + 2] = o1;
    pa[h + 4] = o2;
    pa[h + 6] = o3;
  }
}

// Spectrum S1 = Q*conj(K): own f from regs, mirror from LDS (pass4 dst).
__device__ __forceinline__ void spectrum_reg(const cf pa[8],
                                             const float2* __restrict__ mir,
                                             float s1r[4], float s1i[4], int tid) {
#pragma unroll
  for (int u = 0; u < 4; ++u) {
    const int f = tid + (u << 8);
    if (f == 0) {
      s1r[u] = pa[0].r * pa[0].i;       // S1[0]    (real)
      s1i[u] = pa[4].r * pa[4].i;       // S1[1024] (real), packed here
    } else {
      const cf a = pa[u];
      const cf am = ldx(mir, 2048 - f);
      const float qr = 0.5f * (a.r + am.r), qi = 0.5f * (a.i - am.i);
      const float kr = 0.5f * (a.i + am.i), ki = 0.5f * (am.r - a.r);
      s1r[u] = qr * kr + qi * ki;
      s1i[u] = qi * kr - qr * ki;
    }
  }
}

// Combine: S2 from pb regs + LDS mirror; lower half of Z kept in pc regs,
// mirror half written to dstZ.
__device__ __forceinline__ void combine_reg(const cf pb[8],
                                            const float2* __restrict__ mir,
                                            const float s1r[4], const float s1i[4],
                                            float2* __restrict__ dstZ,
                                            cf pc[4], int tid) {
#pragma unroll
  for (int u = 0; u < 4; ++u) {
    const int f = tid + (u << 8);
    if (f == 0) {
      const float s2_0 = pb[0].r * pb[0].i;
      const float s2_n = pb[4].r * pb[4].i;
      pc[0] = {s1r[0], s2_0};
      stx(dstZ, 1024, {s1i[0], s2_n});
    } else {
      const cf a = pb[u];
      const cf am = ldx(mir, 2048 - f);
      const float qr = 0.5f * (a.r + am.r), qi = 0.5f * (a.i - am.i);
      const float kr = 0.5f * (a.i + am.i), ki = 0.5f * (am.r - a.r);
      const float s2r = qr * kr + qi * ki, s2i = qi * kr - qr * ki;
      pc[u] = {s1r[u] - s2i,  s1i[u] + s2r};
      stx(dstZ, 2048 - f, {s1r[u] + s2i, -s1i[u] + s2r});
    }
  }
}

// Dual inverse pass 1 (s=1): lower halves from pc regs; shared twiddles.
__device__ __forceinline__ void inv_pass1_dual(const cf pcA[4],
                                               const float2* __restrict__ ZA,
                                               float2* __restrict__ dA,
                                               const cf pcB[4],
                                               const float2* __restrict__ ZB,
                                               float2* __restrict__ dB, int tid) {
  cf a[8], bA[8], a2[8], bB[8];
#pragma unroll
  for (int l = 0; l < 8; ++l) {
    a[l]  = (l < 4) ? pcA[l] : ldx(ZA, tid + (l << 8));
    a2[l] = (l < 4) ? pcB[l] : ldx(ZB, tid + (l << 8));
  }
  dft8<true>(a, bA);
  dft8<true>(a2, bB);
  const tw7 t = make_tw(tid, -ANG_);
  apply_tw(bA, t);
  apply_tw(bB, t);
#pragma unroll
  for (int k = 0; k < 8; ++k) {
    stx(dA, 8 * tid + k, bA[k]);
    stx(dB, 8 * tid + k, bB[k]);
  }
}

// Inverse final radix-4 fused with the bf16 global store (Re->c0, Im->c1).
__device__ __forceinline__ void pass4_last(const float2* __restrict__ src,
                                           ushort* __restrict__ c0,
                                           ushort* __restrict__ c1, int j) {
  const float inv = 1.0f / (float)L_;
#pragma unroll
  for (int h = 0; h < 2; ++h) {
    const int jj = j + (h << 8);
    cf a0 = ldx(src, jj), a1 = ldx(src, jj + 512), a2 = ldx(src, jj + 1024), a3 = ldx(src, jj + 1536);
    cf s0 = cadd(a0,a2), s1 = csub(a0,a2), s2 = cadd(a1,a3), s3 = rot90<true>(csub(a1,a3));
    const cf o0 = cadd(s0,s2), o1 = cadd(s1,s3), o2 = csub(s0,s2), o3 = csub(s1,s3);
    c0[jj]        = f2bf(o0.r * inv);  c1[jj]        = f2bf(o0.i * inv);
    c0[jj + 512]  = f2bf(o1.r * inv);  c1[jj + 512]  = f2bf(o1.i * inv);
    c0[jj + 1024] = f2bf(o2.r * inv);  c1[jj + 1024] = f2bf(o2.i * inv);
    c0[jj + 1536] = f2bf(o3.r * inv);  c1[jj + 1536] = f2bf(o3.i * inv);
  }
}

__global__ __launch_bounds__(256) void kB(const ushort* __restrict__ qT,
                                          const ushort* __restrict__ kT,
                                          ushort* __restrict__ corrT) {
  __shared__ float2 U0[L_], U1[L_], U2[L_], U3[L_];   // 64 KiB
  const int tid = threadIdx.x;
  const size_t r0 = (size_t)(blockIdx.x * 4) * L_;
  const size_t r1 = r0 + L_, r2 = r0 + 2 * L_, r3 = r0 + 3 * L_;

  // ---- phase 1: forward ch0 (alpha: U0/U1) and ch1 (beta: U2/U3) ----
  pass8_first_dual(qT + r0, kT + r0, U0, qT + r1, kT + r1, U2, tid);
  __syncthreads();
  pass8_dual<3, false>(U0, U1, U2, U3, tid);
  __syncthreads();
  pass8_dual<6, false>(U1, U0, U3, U2, tid);
  __syncthreads();
  cf paA[8], paB[8];
  pass4_fwd_reg(U0, U1, tid, paA);
  pass4_fwd_reg(U2, U3, tid, paB);
  __syncthreads();

  float s1rA[4], s1iA[4], s1rB[4], s1iB[4];
  spectrum_reg(paA, U1, s1rA, s1iA, tid);   // reads U1 (done before next bar)
  spectrum_reg(paB, U3, s1rB, s1iB, tid);   // reads U3

  // ---- phase 2: forward ch2 (alpha) and ch3 (beta) ----
  pass8_first_dual(qT + r2, kT + r2, U0, qT + r3, kT + r3, U2, tid);
  __syncthreads();                          // U0/U2 writes don't touch U1/U3
  pass8_dual<3, false>(U0, U1, U2, U3, tid);
  __syncthreads();
  pass8_dual<6, false>(U1, U0, U3, U2, tid);
  __syncthreads();
  cf pbA[8], pbB[8];
  pass4_fwd_reg(U0, U1, tid, pbA);
  pass4_fwd_reg(U2, U3, tid, pbB);
  __syncthreads();

  // ---- combine: Z_A = S1(ch0)+i*S2(ch2) -> U0 ; Z_B = S1(ch1)+i*S2(ch3) -> U2
  cf pcA[4], pcB[4];
  combine_reg(pbA, U1, s1rA, s1iA, U0, pcA, tid);
  combine_reg(pbB, U3, s1rB, s1iB, U2, pcB, tid);
  __syncthreads();

  // ---- packed inverses (alpha: U0->U1->U0->U1 ; beta: U2->U3->U2->U3) ----
  inv_pass1_dual(pcA, U0, U1, pcB, U2, U3, tid);
  __syncthreads();
  pass8_dual<3, true>(U1, U0, U3, U2, tid);
  __syncthreads();
  pass8_dual<6, true>(U0, U1, U2, U3, tid);
  __syncthreads();
  pass4_last(U1, corrT + r0, corrT + r2, tid);   // alpha: Re->ch0, Im->ch2
  pass4_last(U3, corrT + r1, corrT + r3, tid);   // beta:  Re->ch1, Im->ch3
}

// ---------------------------------------------------------------------------
// Kernel C: transpose corrT bf16 (B,D,L) -> corr_out f32 (B,L,D)
// + per-(b,dtile) sums. 64x64 tiles.
// ---------------------------------------------------------------------------
__global__ __launch_bounds__(256) void kC(const ushort* __restrict__ corrT,
                                          float* __restrict__ corrOut,
                                          float* __restrict__ partial) {
  __shared__ float t[64][65];
  const int t0 = blockIdx.x * 64, d0 = blockIdx.y * 64, b = blockIdx.z;
  const int tid = threadIdx.x;
#pragma unroll
  for (int u = 0; u < 4; ++u) {
    const int idx  = tid + (u << 8);
    const int drow = idx >> 4;               // d within tile
    const int c    = (idx & 15) << 2;        // tau within tile (ushort4)
    const ushort4 v = *(const ushort4*)&corrT[((size_t)b * D_ + d0 + drow) * L_ + t0 + c];
    t[drow][c + 0] = bf2f(v.x); t[drow][c + 1] = bf2f(v.y);
    t[drow][c + 2] = bf2f(v.z); t[drow][c + 3] = bf2f(v.w);
  }
  __syncthreads();
#pragma unroll
  for (int u = 0; u < 4; ++u) {
    const int idx  = tid + (u << 8);
    const int trow = idx >> 4;               // tau within tile
    const int c    = (idx & 15) << 2;        // d within tile (float4)
    float4 o;
    o.x = t[c + 0][trow]; o.y = t[c + 1][trow];
    o.z = t[c + 2][trow]; o.w = t[c + 3][trow];
    *(float4*)&corrOut[((size_t)b * L_ + t0 + trow) * D_ + d0 + c] = o;
  }
  if (tid < 64) {                            // one thread per tau
    float s = 0.f;
#pragma unroll
    for (int i = 0; i < 64; ++i) s += t[i][tid];
    partial[((size_t)b * 8 + blockIdx.y) * L_ + t0 + tid] = s;
  }
}

// ---------------------------------------------------------------------------
// Kernel D0: reduce partial[128][L] -> g[L]  (32 blocks, deterministic)
// ---------------------------------------------------------------------------
__global__ __launch_bounds__(256) void kD0(const float* __restrict__ partial,
                                           float* __restrict__ g) {
  __shared__ float red[4][64];
  const int tl = threadIdx.x & 63, rg = threadIdx.x >> 6;
  const int tau = blockIdx.x * 64 + tl;
  float s = 0.f;
  for (int i = rg; i < 128; i += 4) s += partial[(size_t)i * L_ + tau];
  red[rg][tl] = s;
  __syncthreads();
  if (rg == 0) g[tau] = red[0][tl] + red[1][tl] + red[2][tl] + red[3][tl];
}

// ---------------------------------------------------------------------------
// Kernel D1: top-7 on g[L]; per-b softmax weights. Single small block.
// R15: wave-level shuffle argmax (total order: value desc, index asc —
// associative, so reduction shape doesn't affect the result).
// ---------------------------------------------------------------------------
__global__ __launch_bounds__(256) void kD1(const float* __restrict__ gin,
                                           const float* __restrict__ partial,
                                           int* __restrict__ oidx,
                                           float* __restrict__ ow) {
  __shared__ float g[L_];
  __shared__ float rv[4];
  __shared__ int   ri[4];
  __shared__ int   sidx[K_];
  const int tid = threadIdx.x;
#pragma unroll
  for (int u = 0; u < 8; ++u) g[tid + u * 256] = gin[tid + u * 256];
  __syncthreads();

  for (int it = 0; it < K_; ++it) {
    float bv = -1e30f; int bix = 1 << 30;
#pragma unroll
    for (int u = 0; u < 8; ++u) {
      const int tau = tid + u * 256;
      const float vv = g[tau];
      if (vv > bv || (vv == bv && tau < bix)) { bv = vv; bix = tau; }
    }
    // 64-lane wave reduce (no barriers)
#pragma unroll
    for (int off = 32; off > 0; off >>= 1) {
      const float ov = __shfl_down(bv, off);
      const int   oi = __shfl_down(bix, off);
      if (ov > bv || (ov == bv && oi < bix)) { bv = ov; bix = oi; }
    }
    if ((tid & 63) == 0) { rv[tid >> 6] = bv; ri[tid >> 6] = bix; }
    __syncthreads();
    if (tid == 0) {
      float fv = rv[0]; int fi = ri[0];
#pragma unroll
      for (int w = 1; w < 4; ++w) {
        if (rv[w] > fv || (rv[w] == fv && ri[w] < fi)) { fv = rv[w]; fi = ri[w]; }
      }
      sidx[it] = fi; g[fi] = -3e38f;
    }
    __syncthreads();
  }

  if (tid < B_) {
    const int b = tid;
    float m[K_]; float mx = -1e30f;
    for (int kk = 0; kk < K_; ++kk) {
      float s = 0.f;
      for (int dt = 0; dt < 8; ++dt)
        s += partial[((size_t)b * 8 + dt) * L_ + sidx[kk]];
      m[kk] = s * (1.0f / 512.0f);
      mx = fmaxf(mx, m[kk]);
    }
    float sum = 0.f;
    for (int kk = 0; kk < K_; ++kk) { m[kk] = expf(m[kk] - mx); sum += m[kk]; }
    const float inv = 1.0f / sum;
    for (int kk = 0; kk < K_; ++kk) ow[b * K_ + kk] = m[kk] * inv;
  }
  if (tid < K_) oidx[tid] = sidx[tid];
}

// ---------------------------------------------------------------------------
// Kernel E: out[b,l,:] = sum_k w[b,k] * v[b, (l+idx[k])%L, :]   (float4)
// ---------------------------------------------------------------------------
__global__ __launch_bounds__(256) void kE(const float4* __restrict__ v4,
                                          const float* __restrict__ w,
                                          const int* __restrict__ idx,
                                          float4* __restrict__ out4) {
  const int bx = blockIdx.x;
  const int b  = bx >> 10;
  const int l  = ((bx & 1023) << 1) | (threadIdx.x >> 7);
  const int j  = threadIdx.x & 127;

  float ww[K_]; int rr[K_];
#pragma unroll
  for (int kk = 0; kk < K_; ++kk) {
    ww[kk] = w[b * K_ + kk];
    int r = l + idx[kk];
    if (r >= L_) r -= L_;
    rr[kk] = r;
  }
  const size_t vb = (size_t)b * L_ * 128;
  float4 acc = make_float4(0.f, 0.f, 0.f, 0.f);
#pragma unroll
  for (int kk = 0; kk < K_; ++kk) {
    const float4 vv = v4[vb + (size_t)rr[kk] * 128 + j];
    acc.x += ww[kk] * vv.x; acc.y += ww[kk] * vv.y;
    acc.z += ww[kk] * vv.z; acc.w += ww[kk] * vv.w;
  }
  out4[vb + (size_t)l * 128 + j] = acc;
}

// ---------------------------------------------------------------------------
extern "C" void kernel_launch(void* const* d_in, const int* in_sizes, int n_in,
                              void* d_out, int out_size, void* d_ws, size_t ws_size,
                              hipStream_t stream) {
  const float* q = (const float*)d_in[0];
  const float* k = (const float*)d_in[1];
  const float* v = (const float*)d_in[2];

  float* out     = (float*)d_out;        // final out  [0, Q_)
  float* corrOut = out + Q_;             // final corr [Q_, 2Q_)
  // bf16 transpose scratch inside d_out (regions dead before overwrite):
  ushort* qT16 = (ushort*)out;           // consumed by kB before kE overwrites
  ushort* kT16 = (ushort*)corrOut;       // consumed by kB before kC overwrites

  ushort* corrT16 = (ushort*)d_ws;                       // Q_ ushorts (32 MB)
  float*  partial = (float*)(corrT16 + Q_);              // 16*8*2048 floats
  float*  g2048   = partial + (size_t)B_ * 8 * L_;       // 2048 floats
  int*    oidx    = (int*)(g2048 + L_);                  // 16 ints
  float*  ow      = (float*)(oidx + 16);                 // 112 floats

  kA<<<dim3(L_ / 64, D_ / 64, B_ * 2), 256, 0, stream>>>(q, k, qT16, kT16);
  kB<<<(B_ * D_) / 4, 256, 0, stream>>>(qT16, kT16, corrT16);
  kC<<<dim3(L_ / 64, D_ / 64, B_), 256, 0, stream>>>(corrT16, corrOut, partial);
  kD0<<<32, 256, 0, stream>>>(partial, g2048);
  kD1<<<1, 256, 0, stream>>>(g2048, partial, oidx, ow);
  kE<<<(B_ * L_) / 2, 256, 0, stream>>>((const float4*)v, ow, oidx, (float4*)out);
}

// Round 16
// 181.483 us; speedup vs baseline: 1.0131x; 1.0131x over previous
//
#include <hip/hip_runtime.h>
#include <math.h>

#define B_  16
#define L_  2048
#define D_  512
#define K_  7
#define Q_  (B_*L_*D_)   // 16777216 elements per output tensor

// bf16 helpers (RNE pack, shift unpack)
__device__ __forceinline__ ushort f2bf(float x){
  uint u = __float_as_uint(x);
  u += 0x7FFFu + ((u >> 16) & 1u);
  return (ushort)(u >> 16);
}
__device__ __forceinline__ float bf2f(ushort h){
  return __uint_as_float((uint)h << 16);
}

// ---------------------------------------------------------------------------
// Kernel A (best form, R8/R11): tiled transpose (B,L,D) f32 -> (B,D,L) bf16.
// One tensor per block -> 16.9 KiB LDS, high concurrency. (Multi-tile
// pipelining regressed twice: R10, R12 — keep one tile / many blocks.)
// ---------------------------------------------------------------------------
__global__ __launch_bounds__(256) void kA(const float* __restrict__ q,
                                          const float* __restrict__ k,
                                          ushort* __restrict__ qT,
                                          ushort* __restrict__ kT) {
  __shared__ float t[64][65];
  const int l0 = blockIdx.x * 64, d0 = blockIdx.y * 64;
  const int b = blockIdx.z & 15, ten = blockIdx.z >> 4;
  const float*  __restrict__ src = ten ? k : q;
  ushort* __restrict__ dst = ten ? kT : qT;
  const int tid = threadIdx.x;
  const size_t ibase = (size_t)b * L_ * D_;
#pragma unroll
  for (int u = 0; u < 4; ++u) {
    const int idx = tid + (u << 8);          // 0..1023
    const int row = idx >> 4;                // l within tile
    const int c   = (idx & 15) << 2;         // d within tile (float4)
    const float4 v = *(const float4*)&src[ibase + (size_t)(l0 + row) * D_ + d0 + c];
    t[row][c + 0] = v.x; t[row][c + 1] = v.y;
    t[row][c + 2] = v.z; t[row][c + 3] = v.w;
  }
  __syncthreads();
  const size_t obase = (size_t)b * D_ * L_;
#pragma unroll
  for (int u = 0; u < 4; ++u) {
    const int idx  = tid + (u << 8);
    const int drow = idx >> 4;               // d within tile
    const int c    = (idx & 15) << 2;        // l within tile (ushort4)
    ushort4 o;
    o.x = f2bf(t[c + 0][drow]); o.y = f2bf(t[c + 1][drow]);
    o.z = f2bf(t[c + 2][drow]); o.w = f2bf(t[c + 3][drow]);
    *(ushort4*)&dst[obase + (size_t)(d0 + drow) * L_ + l0 + c] = o;
  }
}

// ---------------------------------------------------------------------------
// Kernel B (R14 form, measured best): 4 channels/block, 256 threads, 64 KiB
// LDS (two independent ping-pong pairs U0/U1 and U2/U3). Every pass runs
// stream alpha AND beta per thread (2 butterflies) with ONE shared barrier.
// All threads always active (R9 lesson); no forced VGPR bound (R4 lesson).
// alpha packs (ch0, ch2) -> rows r0/r2; beta packs (ch1, ch3) -> rows r1/r3.
// ---------------------------------------------------------------------------
struct cf { float r, i; };
__device__ __forceinline__ cf cadd(cf a, cf b){ return {a.r+b.r, a.i+b.i}; }
__device__ __forceinline__ cf csub(cf a, cf b){ return {a.r-b.r, a.i-b.i}; }
__device__ __forceinline__ cf cmul(cf a, cf b){ return {a.r*b.r - a.i*b.i, a.r*b.i + a.i*b.r}; }
template<bool INV> __device__ __forceinline__ cf rot90(cf x){
  return INV ? cf{-x.i, x.r} : cf{x.i, -x.r};   // * +/- i
}
__device__ __forceinline__ int swz(int a){ return a ^ (((a >> 4) ^ (a >> 8)) & 15); }
__device__ __forceinline__ cf ldx(const float2* __restrict__ p, int i){
  const float2 v = p[swz(i)]; return {v.x, v.y};
}
__device__ __forceinline__ void stx(float2* __restrict__ p, int i, cf v){
  p[swz(i)] = {v.r, v.i};
}

template<bool INV>
__device__ __forceinline__ void dft8(cf a[8], cf b[8]) {
  const float H = 0.70710678118654752440f;
  cf t0 = cadd(a[0],a[4]), t1 = cadd(a[1],a[5]), t2 = cadd(a[2],a[6]), t3 = cadd(a[3],a[7]);
  cf u0 = csub(a[0],a[4]), u1 = csub(a[1],a[5]), u2 = csub(a[2],a[6]), u3 = csub(a[3],a[7]);
  const cf w1 = INV ? cf{H,  H} : cf{ H, -H};
  const cf w3 = INV ? cf{-H, H} : cf{-H, -H};
  u1 = cmul(u1, w1);
  u2 = rot90<INV>(u2);
  u3 = cmul(u3, w3);
  { cf s0 = cadd(t0,t2), s1 = csub(t0,t2), s2 = cadd(t1,t3), s3 = rot90<INV>(csub(t1,t3));
    b[0]=cadd(s0,s2); b[4]=csub(s0,s2); b[2]=cadd(s1,s3); b[6]=csub(s1,s3); }
  { cf s0 = cadd(u0,u2), s1 = csub(u0,u2), s2 = cadd(u1,u3), s3 = rot90<INV>(csub(u1,u3));
    b[1]=cadd(s0,s2); b[5]=csub(s0,s2); b[3]=cadd(s1,s3); b[7]=csub(s1,s3); }
}

// Apply twiddles w^1..w^7 (log-depth chain) and store (Stockham scatter).
template<int LOG2S>
__device__ __forceinline__ void twiddle_store(cf b[8], float2* __restrict__ dst,
                                              int j, int p, float sgn_ang) {
  float sn, cs;
  __sincosf(sgn_ang * (float)(p << LOG2S), &sn, &cs);
  const cf w1{cs, sn};
  const cf w2 = cmul(w1, w1);
  const cf w3 = cmul(w2, w1);
  const cf w4 = cmul(w2, w2);
  const cf w5 = cmul(w3, w2);
  const cf w6 = cmul(w3, w3);
  const cf w7 = cmul(w4, w3);
  b[1] = cmul(b[1], w1); b[2] = cmul(b[2], w2); b[3] = cmul(b[3], w3);
  b[4] = cmul(b[4], w4); b[5] = cmul(b[5], w5); b[6] = cmul(b[6], w6);
  b[7] = cmul(b[7], w7);
  const int wb = j + 7 * (p << LOG2S);
#pragma unroll
  for (int k = 0; k < 8; ++k) stx(dst, wb + (k << LOG2S), b[k]);
}

#define ANG_ (-0.0030679615757712823f)   // -2*pi/2048

// Forward pass 1 fused with bf16 global load: z[l] = q[l] + i*k[l].
__device__ __forceinline__ void pass8_first(const ushort* __restrict__ qg,
                                            const ushort* __restrict__ kg,
                                            float2* __restrict__ dst, int j) {
  cf a[8], b[8];
#pragma unroll
  for (int l = 0; l < 8; ++l) {
    const int ix = j + (l << 8);
    a[l] = {bf2f(qg[ix]), bf2f(kg[ix])};
  }
  dft8<false>(a, b);
  twiddle_store<0>(b, dst, j, j, ANG_);
}

template<int LOG2S, bool INV>
__device__ __forceinline__ void pass8f2(const float2* __restrict__ src,
                                        float2* __restrict__ dst, int j) {
  const int p = j >> LOG2S;
  cf a[8], b[8];
#pragma unroll
  for (int l = 0; l < 8; ++l) a[l] = ldx(src, j + (l << 8));
  dft8<INV>(a, b);
  twiddle_store<LOG2S>(b, dst, j, p, INV ? -ANG_ : ANG_);
}

// Forward final radix-4 (s=512, twiddle-free), LDS->LDS, outputs ALSO kept
// in regs: pa[m] holds f = j + 256m.
__device__ __forceinline__ void pass4_fwd_reg(const float2* __restrict__ src,
                                              float2* __restrict__ dst, int j,
                                              cf pa[8]) {
#pragma unroll
  for (int h = 0; h < 2; ++h) {
    const int jj = j + (h << 8);
    cf a0 = ldx(src, jj), a1 = ldx(src, jj + 512), a2 = ldx(src, jj + 1024), a3 = ldx(src, jj + 1536);
    cf s0 = cadd(a0,a2), s1 = csub(a0,a2), s2 = cadd(a1,a3), s3 = rot90<false>(csub(a1,a3));
    const cf o0 = cadd(s0,s2), o1 = cadd(s1,s3), o2 = csub(s0,s2), o3 = csub(s1,s3);
    stx(dst, jj,        o0);
    stx(dst, jj + 512,  o1);
    stx(dst, jj + 1024, o2);
    stx(dst, jj + 1536, o3);
    pa[h]     = o0;
    pa[h + 2] = o1;
    pa[h + 4] = o2;
    pa[h + 6] = o3;
  }
}

// Spectrum S1 = Q*conj(K): own f from regs, mirror from LDS (pass4 dst).
__device__ __forceinline__ void spectrum_reg(const cf pa[8],
                                             const float2* __restrict__ mir,
                                             float s1r[4], float s1i[4], int tid) {
#pragma unroll
  for (int u = 0; u < 4; ++u) {
    const int f = tid + (u << 8);
    if (f == 0) {
      s1r[u] = pa[0].r * pa[0].i;       // S1[0]    (real)
      s1i[u] = pa[4].r * pa[4].i;       // S1[1024] (real), packed here
    } else {
      const cf a = pa[u];
      const cf am = ldx(mir, 2048 - f);
      const float qr = 0.5f * (a.r + am.r), qi = 0.5f * (a.i - am.i);
      const float kr = 0.5f * (a.i + am.i), ki = 0.5f * (am.r - a.r);
      s1r[u] = qr * kr + qi * ki;
      s1i[u] = qi * kr - qr * ki;
    }
  }
}

// Combine: S2 from pb regs + LDS mirror; lower half of Z kept in pc regs,
// mirror half written to dstZ.
__device__ __forceinline__ void combine_reg(const cf pb[8],
                                            const float2* __restrict__ mir,
                                            const float s1r[4], const float s1i[4],
                                            float2* __restrict__ dstZ,
                                            cf pc[4], int tid) {
#pragma unroll
  for (int u = 0; u < 4; ++u) {
    const int f = tid + (u << 8);
    if (f == 0) {
      const float s2_0 = pb[0].r * pb[0].i;
      const float s2_n = pb[4].r * pb[4].i;
      pc[0] = {s1r[0], s2_0};
      stx(dstZ, 1024, {s1i[0], s2_n});
    } else {
      const cf a = pb[u];
      const cf am = ldx(mir, 2048 - f);
      const float qr = 0.5f * (a.r + am.r), qi = 0.5f * (a.i - am.i);
      const float kr = 0.5f * (a.i + am.i), ki = 0.5f * (am.r - a.r);
      const float s2r = qr * kr + qi * ki, s2i = qi * kr - qr * ki;
      pc[u] = {s1r[u] - s2i,  s1i[u] + s2r};
      stx(dstZ, 2048 - f, {s1r[u] + s2i, -s1i[u] + s2r});
    }
  }
}

// Inverse pass 1 (s=1): lower half from pc regs, upper half from Zup LDS.
__device__ __forceinline__ void inv_pass1(const cf pc[4],
                                          const float2* __restrict__ Zup,
                                          float2* __restrict__ dst, int tid) {
  cf a[8], b[8];
#pragma unroll
  for (int l = 0; l < 8; ++l)
    a[l] = (l < 4) ? pc[l] : ldx(Zup, tid + (l << 8));
  dft8<true>(a, b);
  twiddle_store<0>(b, dst, tid, tid, -ANG_);
}

// Inverse final radix-4 fused with the bf16 global store (Re->c0, Im->c1).
__device__ __forceinline__ void pass4_last(const float2* __restrict__ src,
                                           ushort* __restrict__ c0,
                                           ushort* __restrict__ c1, int j) {
  const float inv = 1.0f / (float)L_;
#pragma unroll
  for (int h = 0; h < 2; ++h) {
    const int jj = j + (h << 8);
    cf a0 = ldx(src, jj), a1 = ldx(src, jj + 512), a2 = ldx(src, jj + 1024), a3 = ldx(src, jj + 1536);
    cf s0 = cadd(a0,a2), s1 = csub(a0,a2), s2 = cadd(a1,a3), s3 = rot90<true>(csub(a1,a3));
    const cf o0 = cadd(s0,s2), o1 = cadd(s1,s3), o2 = csub(s0,s2), o3 = csub(s1,s3);
    c0[jj]        = f2bf(o0.r * inv);  c1[jj]        = f2bf(o0.i * inv);
    c0[jj + 512]  = f2bf(o1.r * inv);  c1[jj + 512]  = f2bf(o1.i * inv);
    c0[jj + 1024] = f2bf(o2.r * inv);  c1[jj + 1024] = f2bf(o2.i * inv);
    c0[jj + 1536] = f2bf(o3.r * inv);  c1[jj + 1536] = f2bf(o3.i * inv);
  }
}

__global__ __launch_bounds__(256) void kB(const ushort* __restrict__ qT,
                                          const ushort* __restrict__ kT,
                                          ushort* __restrict__ corrT) {
  __shared__ float2 U0[L_], U1[L_], U2[L_], U3[L_];   // 64 KiB
  const int tid = threadIdx.x;
  const size_t r0 = (size_t)(blockIdx.x * 4) * L_;
  const size_t r1 = r0 + L_, r2 = r0 + 2 * L_, r3 = r0 + 3 * L_;

  // ---- phase 1: forward ch0 (alpha: U0/U1) and ch1 (beta: U2/U3) ----
  pass8_first(qT + r0, kT + r0, U0, tid);
  pass8_first(qT + r1, kT + r1, U2, tid);
  __syncthreads();
  pass8f2<3, false>(U0, U1, tid);
  pass8f2<3, false>(U2, U3, tid);
  __syncthreads();
  pass8f2<6, false>(U1, U0, tid);
  pass8f2<6, false>(U3, U2, tid);
  __syncthreads();
  cf paA[8], paB[8];
  pass4_fwd_reg(U0, U1, tid, paA);
  pass4_fwd_reg(U2, U3, tid, paB);
  __syncthreads();

  float s1rA[4], s1iA[4], s1rB[4], s1iB[4];
  spectrum_reg(paA, U1, s1rA, s1iA, tid);   // reads U1 (done before next bar)
  spectrum_reg(paB, U3, s1rB, s1iB, tid);   // reads U3

  // ---- phase 2: forward ch2 (alpha) and ch3 (beta) ----
  pass8_first(qT + r2, kT + r2, U0, tid);   // writes U0/U2 only: no conflict
  pass8_first(qT + r3, kT + r3, U2, tid);   // with the spectrum reads above
  __syncthreads();
  pass8f2<3, false>(U0, U1, tid);
  pass8f2<3, false>(U2, U3, tid);
  __syncthreads();
  pass8f2<6, false>(U1, U0, tid);
  pass8f2<6, false>(U3, U2, tid);
  __syncthreads();
  cf pbA[8], pbB[8];
  pass4_fwd_reg(U0, U1, tid, pbA);
  pass4_fwd_reg(U2, U3, tid, pbB);
  __syncthreads();

  // ---- combine: Z_A = S1(ch0)+i*S2(ch2) -> U0 ; Z_B = S1(ch1)+i*S2(ch3) -> U2
  cf pcA[4], pcB[4];
  combine_reg(pbA, U1, s1rA, s1iA, U0, pcA, tid);
  combine_reg(pbB, U3, s1rB, s1iB, U2, pcB, tid);
  __syncthreads();

  // ---- packed inverses (alpha: U0->U1->U0->U1 ; beta: U2->U3->U2->U3) ----
  inv_pass1(pcA, U0, U1, tid);
  inv_pass1(pcB, U2, U3, tid);
  __syncthreads();
  pass8f2<3, true>(U1, U0, tid);
  pass8f2<3, true>(U3, U2, tid);
  __syncthreads();
  pass8f2<6, true>(U0, U1, tid);
  pass8f2<6, true>(U2, U3, tid);
  __syncthreads();
  pass4_last(U1, corrT + r0, corrT + r2, tid);   // alpha: Re->ch0, Im->ch2
  pass4_last(U3, corrT + r1, corrT + r3, tid);   // beta:  Re->ch1, Im->ch3
}

// ---------------------------------------------------------------------------
// Kernel C: transpose corrT bf16 (B,D,L) -> corr_out f32 (B,L,D)
// + per-(b,dtile) sums. 64x64 tiles.
// ---------------------------------------------------------------------------
__global__ __launch_bounds__(256) void kC(const ushort* __restrict__ corrT,
                                          float* __restrict__ corrOut,
                                          float* __restrict__ partial) {
  __shared__ float t[64][65];
  const int t0 = blockIdx.x * 64, d0 = blockIdx.y * 64, b = blockIdx.z;
  const int tid = threadIdx.x;
#pragma unroll
  for (int u = 0; u < 4; ++u) {
    const int idx  = tid + (u << 8);
    const int drow = idx >> 4;               // d within tile
    const int c    = (idx & 15) << 2;        // tau within tile (ushort4)
    const ushort4 v = *(const ushort4*)&corrT[((size_t)b * D_ + d0 + drow) * L_ + t0 + c];
    t[drow][c + 0] = bf2f(v.x); t[drow][c + 1] = bf2f(v.y);
    t[drow][c + 2] = bf2f(v.z); t[drow][c + 3] = bf2f(v.w);
  }
  __syncthreads();
#pragma unroll
  for (int u = 0; u < 4; ++u) {
    const int idx  = tid + (u << 8);
    const int trow = idx >> 4;               // tau within tile
    const int c    = (idx & 15) << 2;        // d within tile (float4)
    float4 o;
    o.x = t[c + 0][trow]; o.y = t[c + 1][trow];
    o.z = t[c + 2][trow]; o.w = t[c + 3][trow];
    *(float4*)&corrOut[((size_t)b * L_ + t0 + trow) * D_ + d0 + c] = o;
  }
  if (tid < 64) {                            // one thread per tau
    float s = 0.f;
#pragma unroll
    for (int i = 0; i < 64; ++i) s += t[i][tid];
    partial[((size_t)b * 8 + blockIdx.y) * L_ + t0 + tid] = s;
  }
}

// ---------------------------------------------------------------------------
// Kernel D0: reduce partial[128][L] -> g[L]  (32 blocks, deterministic)
// ---------------------------------------------------------------------------
__global__ __launch_bounds__(256) void kD0(const float* __restrict__ partial,
                                           float* __restrict__ g) {
  __shared__ float red[4][64];
  const int tl = threadIdx.x & 63, rg = threadIdx.x >> 6;
  const int tau = blockIdx.x * 64 + tl;
  float s = 0.f;
  for (int i = rg; i < 128; i += 4) s += partial[(size_t)i * L_ + tau];
  red[rg][tl] = s;
  __syncthreads();
  if (rg == 0) g[tau] = red[0][tl] + red[1][tl] + red[2][tl] + red[3][tl];
}

// ---------------------------------------------------------------------------
// Kernel D1: top-7 on g[L]; per-b softmax weights. Single small block.
// ---------------------------------------------------------------------------
__global__ __launch_bounds__(256) void kD1(const float* __restrict__ gin,
                                           const float* __restrict__ partial,
                                           int* __restrict__ oidx,
                                           float* __restrict__ ow) {
  __shared__ float g[L_];
  __shared__ float rv[256];
  __shared__ int   ri[256];
  __shared__ int   sidx[K_];
  const int tid = threadIdx.x;
#pragma unroll
  for (int u = 0; u < 8; ++u) g[tid + u * 256] = gin[tid + u * 256];
  __syncthreads();

  for (int it = 0; it < K_; ++it) {
    float bv = -1e30f; int bix = 1 << 30;
#pragma unroll
    for (int u = 0; u < 8; ++u) {
      const int tau = tid + u * 256;
      const float vv = g[tau];
      if (vv > bv || (vv == bv && tau < bix)) { bv = vv; bix = tau; }
    }
    rv[tid] = bv; ri[tid] = bix;
    __syncthreads();
    for (int off = 128; off > 0; off >>= 1) {
      if (tid < off) {
        const float v2 = rv[tid + off]; const int i2 = ri[tid + off];
        if (v2 > rv[tid] || (v2 == rv[tid] && i2 < ri[tid])) {
          rv[tid] = v2; ri[tid] = i2;
        }
      }
      __syncthreads();
    }
    if (tid == 0) { sidx[it] = ri[0]; g[ri[0]] = -3e38f; }
    __syncthreads();
  }

  if (tid < B_) {
    const int b = tid;
    float m[K_]; float mx = -1e30f;
    for (int kk = 0; kk < K_; ++kk) {
      float s = 0.f;
      for (int dt = 0; dt < 8; ++dt)
        s += partial[((size_t)b * 8 + dt) * L_ + sidx[kk]];
      m[kk] = s * (1.0f / 512.0f);
      mx = fmaxf(mx, m[kk]);
    }
    float sum = 0.f;
    for (int kk = 0; kk < K_; ++kk) { m[kk] = expf(m[kk] - mx); sum += m[kk]; }
    const float inv = 1.0f / sum;
    for (int kk = 0; kk < K_; ++kk) ow[b * K_ + kk] = m[kk] * inv;
  }
  if (tid < K_) oidx[tid] = sidx[tid];
}

// ---------------------------------------------------------------------------
// Kernel E: out[b,l,:] = sum_k w[b,k] * v[b, (l+idx[k])%L, :]   (float4)
// ---------------------------------------------------------------------------
__global__ __launch_bounds__(256) void kE(const float4* __restrict__ v4,
                                          const float* __restrict__ w,
                                          const int* __restrict__ idx,
                                          float4* __restrict__ out4) {
  const int bx = blockIdx.x;
  const int b  = bx >> 10;
  const int l  = ((bx & 1023) << 1) | (threadIdx.x >> 7);
  const int j  = threadIdx.x & 127;

  float ww[K_]; int rr[K_];
#pragma unroll
  for (int kk = 0; kk < K_; ++kk) {
    ww[kk] = w[b * K_ + kk];
    int r = l + idx[kk];
    if (r >= L_) r -= L_;
    rr[kk] = r;
  }
  const size_t vb = (size_t)b * L_ * 128;
  float4 acc = make_float4(0.f, 0.f, 0.f, 0.f);
#pragma unroll
  for (int kk = 0; kk < K_; ++kk) {
    const float4 vv = v4[vb + (size_t)rr[kk] * 128 + j];
    acc.x += ww[kk] * vv.x; acc.y += ww[kk] * vv.y;
    acc.z += ww[kk] * vv.z; acc.w += ww[kk] * vv.w;
  }
  out4[vb + (size_t)l * 128 + j] = acc;
}

// ---------------------------------------------------------------------------
extern "C" void kernel_launch(void* const* d_in, const int* in_sizes, int n_in,
                              void* d_out, int out_size, void* d_ws, size_t ws_size,
                              hipStream_t stream) {
  const float* q = (const float*)d_in[0];
  const float* k = (const float*)d_in[1];
  const float* v = (const float*)d_in[2];

  float* out     = (float*)d_out;        // final out  [0, Q_)
  float* corrOut = out + Q_;             // final corr [Q_, 2Q_)
  // bf16 transpose scratch inside d_out (regions dead before overwrite):
  ushort* qT16 = (ushort*)out;           // consumed by kB before kE overwrites
  ushort* kT16 = (ushort*)corrOut;       // consumed by kB before kC overwrites

  ushort* corrT16 = (ushort*)d_ws;                       // Q_ ushorts (32 MB)
  float*  partial = (float*)(corrT16 + Q_);              // 16*8*2048 floats
  float*  g2048   = partial + (size_t)B_ * 8 * L_;       // 2048 floats
  int*    oidx    = (int*)(g2048 + L_);                  // 16 ints
  float*  ow      = (float*)(oidx + 16);                 // 112 floats

  kA<<<dim3(L_ / 64, D_ / 64, B_ * 2), 256, 0, stream>>>(q, k, qT16, kT16);
  kB<<<(B_ * D_) / 4, 256, 0, stream>>>(qT16, kT16, corrT16);
  kC<<<dim3(L_ / 64, D_ / 64, B_), 256, 0, stream>>>(corrT16, corrOut, partial);
  kD0<<<32, 256, 0, stream>>>(partial, g2048);
  kD1<<<1, 256, 0, stream>>>(g2048, partial, oidx, ow);
  kE<<<(B_ * L_) / 2, 256, 0, stream>>>((const float4*)v, ow, oidx, (float4*)out);
}